// Round 18
// baseline (230.945 us; speedup 1.0000x reference)
//
#include <hip/hip_runtime.h>
#include <hip/hip_bf16.h>
#include <math.h>
#include <float.h>

#define NBG 128      // graphs
#define NND 512      // nodes per graph
#define KNN 6
#define NB_TOT (NBG*NND)
#define HF 256
#define NSTEP1 5     // layer-1 K padded to 160 (131 real)

typedef short bf16x8 __attribute__((ext_vector_type(8)));
typedef float f32x4 __attribute__((ext_vector_type(4)));

// byte offset of element (row, kbyte) in a [rows][32 k] bf16 plane,
// XOR-swizzled so 16-lane frag reads cover all eight 16-B slots (2-way free).
__device__ __forceinline__ int swzoff(int row, int kbyte) {
    return (row*64 + kbyte) ^ (((row>>1)&3)<<4);
}

__device__ __forceinline__ void split_store(const float* v, char* hi_p, char* lo_p) {
    bf16x8 hi, lo;
    #pragma unroll
    for (int j = 0; j < 8; ++j) {
        __hip_bfloat16 h = __float2bfloat16(v[j]);
        float hf = __bfloat162float(h);
        __hip_bfloat16 l = __float2bfloat16(v[j] - hf);
        hi[j] = *(short*)&h;
        lo[j] = *(short*)&l;
    }
    *(bf16x8*)hi_p = hi;
    *(bf16x8*)lo_p = lo;
}

// XCD-aware bijective block swizzle (grid must be a multiple of 8).
__device__ __forceinline__ int xcd_swz(int bid, int grid) {
    return (bid & 7) * (grid >> 3) + (bid >> 3);
}

// ---------------------------------------------------------------------------
// kNN v4b (proven 47 us): 8 blocks/graph, 4 lanes/node, 128 candidates/lane
// as 2 independent branchless (d2,idx) chains.
// ---------------------------------------------------------------------------
__global__ __launch_bounds__(256) void knn_kernel(const float* __restrict__ pos,
                                                  unsigned short* __restrict__ nbr)
{
    const int blk = blockIdx.x;           // 1024 blocks
    const int g = blk >> 3;
    const int chunk = (blk & 7) * 64;
    const int tid = threadIdx.x;
    const int node = chunk + (tid >> 2);  // local node id
    const int sub = tid & 3;

    __shared__ float4 p4[NND + (NND>>6)]; // padded: idx j -> j + (j>>6)
    const float* pg = pos + (size_t)g * NND * 3;
    for (int n = tid; n < NND; n += 256) {
        float x = pg[n*3+0], y = pg[n*3+1], z = pg[n*3+2];
        p4[n + (n>>6)] = make_float4(x, y, z, x*x + y*y + z*z);
    }
    __syncthreads();

    const float4 pi = p4[node + (node>>6)];
    const float m2x = -2.0f*pi.x, m2y = -2.0f*pi.y, m2z = -2.0f*pi.z;

    float bdA[KNN], bdB[KNN]; int biA[KNN], biB[KNN];
    #pragma unroll
    for (int q = 0; q < KNN; ++q) {
        bdA[q] = FLT_MAX; biA[q] = 0x7fffffff;
        bdB[q] = FLT_MAX; biB[q] = 0x7fffffff;
    }

    const int j0 = sub * 128;
    const float4* baseA = &p4[sub*130];
    const float4* baseB = &p4[sub*130 + 65];

    #pragma unroll 2
    for (int t = 0; t < 64; ++t) {
        int ja = j0 + t, jb = j0 + 64 + t;
        float4 pa = baseA[t];
        float4 pb = baseB[t];
        float da = fmaf(m2z, pa.z, fmaf(m2y, pa.y, fmaf(m2x, pa.x, pa.w)));
        float db = fmaf(m2z, pb.z, fmaf(m2y, pb.y, fmaf(m2x, pb.x, pb.w)));
        da = (ja == node) ? FLT_MAX : da;
        db = (jb == node) ? FLT_MAX : db;
        float ca = da; int ia = ja;
        float cb = db; int ib = jb;
        #pragma unroll
        for (int q = 0; q < KNN; ++q) {
            bool sa = ca < bdA[q];
            float t1 = sa ? ca : bdA[q]; float t2 = sa ? bdA[q] : ca;
            int   t3 = sa ? ia : biA[q]; int   t4 = sa ? biA[q] : ia;
            bdA[q] = t1; ca = t2; biA[q] = t3; ia = t4;
            bool sb = cb < bdB[q];
            float u1 = sb ? cb : bdB[q]; float u2 = sb ? bdB[q] : cb;
            int   u3 = sb ? ib : biB[q]; int   u4 = sb ? biB[q] : ib;
            bdB[q] = u1; cb = u2; biB[q] = u3; ib = u4;
        }
    }

    // local merge of chains A and B (min-trick + bubble sort network)
    float ld[KNN]; int li[KNN];
    #pragma unroll
    for (int q = 0; q < KNN; ++q) {
        float ad = bdA[q], xd = bdB[KNN-1-q];
        int   ai = biA[q], xi = biB[KNN-1-q];
        bool t = (ad < xd) || (ad == xd && ai < xi);
        ld[q] = t ? ad : xd;
        li[q] = t ? ai : xi;
    }
    #pragma unroll
    for (int pass = 0; pass < KNN-1; ++pass)
        #pragma unroll
        for (int a = 0; a < KNN-1-pass; ++a) {
            int b = a+1;
            bool sw = (ld[b] < ld[a]) || (ld[b] == ld[a] && li[b] < li[a]);
            float td = sw ? ld[b] : ld[a]; float ud = sw ? ld[a] : ld[b];
            int   ti = sw ? li[b] : li[a]; int   ui = sw ? li[a] : li[b];
            ld[a] = td; li[a] = ti; ld[b] = ud; li[b] = ui;
        }

    // cross-lane merges: partner masks 1 then 2 (4 lanes per node)
    #pragma unroll
    for (int mi = 0; mi < 2; ++mi) {
        const int mask = 1 << mi;
        float od[KNN]; int oi[KNN];
        #pragma unroll
        for (int q = 0; q < KNN; ++q) {
            od[q] = __shfl_xor(ld[q], mask);
            oi[q] = __shfl_xor(li[q], mask);
        }
        #pragma unroll
        for (int q = 0; q < KNN; ++q) {
            float ad = ld[q], xd = od[KNN-1-q];
            int   ai = li[q], xi = oi[KNN-1-q];
            bool t = (ad < xd) || (ad == xd && ai < xi);
            ld[q] = t ? ad : xd;
            li[q] = t ? ai : xi;
        }
        #pragma unroll
        for (int pass = 0; pass < KNN-1; ++pass)
            #pragma unroll
            for (int a = 0; a < KNN-1-pass; ++a) {
                int b = a+1;
                bool sw = (ld[b] < ld[a]) || (ld[b] == ld[a] && li[b] < li[a]);
                float td = sw ? ld[b] : ld[a]; float ud = sw ? ld[a] : ld[b];
                int   ti = sw ? li[b] : li[a]; int   ui = sw ? li[a] : li[b];
                ld[a] = td; li[a] = ti; ld[b] = ud; li[b] = ui;
            }
    }

    if (sub == 0) {
        int base = (g*NND + node)*KNN;
        #pragma unroll
        for (int q = 0; q < KNN; ++q) nbr[base+q] = (unsigned short)li[q];
    }
}

// ---------------------------------------------------------------------------
// W pre-pass (all 3 layers fused): build swizzled hi/lo bf16 images of W.
// ---------------------------------------------------------------------------
__global__ __launch_bounds__(256) void prew_all(
    const float* __restrict__ W1, const float* __restrict__ W2,
    const float* __restrict__ W3,
    char* __restrict__ I1, char* __restrict__ I2, char* __restrict__ I3)
{
    int b = blockIdx.x;
    const float* W; char* img; int K, nstep;
    if (b < 20)      { W = W1; img = I1; K = 131; nstep = 5; }
    else if (b < 52) { W = W2; img = I2; K = 256; nstep = 8; b -= 20; }
    else             { W = W3; img = I3; K = 256; nstep = 8; b -= 52; }
    int gid = b*256 + threadIdx.x;
    int per_nb = nstep*512;
    int nb = gid / per_nb;
    int r  = gid - nb*per_nb;
    int step = r >> 9;
    int r2 = r & 511;
    int cl = r2 >> 2;
    int kc = (r2 & 3) * 8;
    float v[8];
    #pragma unroll
    for (int j = 0; j < 8; ++j) {
        int gk = step*32 + kc + j;
        v[j] = (gk < K) ? W[(size_t)gk*256 + nb*128 + cl] : 0.f;
    }
    char* base = img + (size_t)nb*nstep*16384 + (size_t)step*16384;
    int off = swzoff(cl, kc*2);
    split_store(v, base + off, base + 8192 + off);
}

// ---------------------------------------------------------------------------
// agg_first: A1 image from concat(x,pos). XCD-swizzled blocks.
// ---------------------------------------------------------------------------
__global__ __launch_bounds__(256) void agg_first(const float* __restrict__ x,
                                                 const float* __restrict__ pos,
                                                 const unsigned short* __restrict__ nbr,
                                                 char* __restrict__ Aimg)
{
    int gid = xcd_swz(blockIdx.x, gridDim.x)*256 + threadIdx.x;   // NB_TOT*20
    int i = gid / 20, ch = gid - i*20;
    const float rs = 1.0f/sqrtf(7.0f);
    const float c1 = rs*rs, c2 = 1.0f/7.0f;
    const int gbase = i & ~(NND-1);
    float v[8];
    if (ch < 16) {
        int jn[KNN];
        #pragma unroll
        for (int q = 0; q < KNN; ++q) jn[q] = gbase + nbr[i*KNN+q];
        const float4* x4 = (const float4*)x;
        int c4 = ch*2;
        float4 s0 = x4[(size_t)i*32 + c4], s1 = x4[(size_t)i*32 + c4 + 1];
        float a0=0,a1=0,a2=0,a3=0,b0=0,b1=0,b2=0,b3=0;
        #pragma unroll
        for (int q = 0; q < KNN; ++q) {
            float4 t0 = x4[(size_t)jn[q]*32 + c4];
            float4 t1 = x4[(size_t)jn[q]*32 + c4 + 1];
            a0+=t0.x; a1+=t0.y; a2+=t0.z; a3+=t0.w;
            b0+=t1.x; b1+=t1.y; b2+=t1.z; b3+=t1.w;
        }
        v[0]=a0*c1+s0.x*c2; v[1]=a1*c1+s0.y*c2; v[2]=a2*c1+s0.z*c2; v[3]=a3*c1+s0.w*c2;
        v[4]=b0*c1+s1.x*c2; v[5]=b1*c1+s1.y*c2; v[6]=b2*c1+s1.z*c2; v[7]=b3*c1+s1.w*c2;
    } else if (ch == 16) {
        int jn[KNN];
        #pragma unroll
        for (int q = 0; q < KNN; ++q) jn[q] = gbase + nbr[i*KNN+q];
        float ax=0, ay=0, az=0;
        #pragma unroll
        for (int q = 0; q < KNN; ++q) {
            ax += pos[(size_t)jn[q]*3+0];
            ay += pos[(size_t)jn[q]*3+1];
            az += pos[(size_t)jn[q]*3+2];
        }
        v[0] = ax*c1 + pos[(size_t)i*3+0]*c2;
        v[1] = ay*c1 + pos[(size_t)i*3+1]*c2;
        v[2] = az*c1 + pos[(size_t)i*3+2]*c2;
        v[3]=v[4]=v[5]=v[6]=v[7]=0.f;
    } else {
        #pragma unroll
        for (int j = 0; j < 8; ++j) v[j] = 0.f;
    }
    int mb = i >> 7, row = i & 127, step = ch >> 2, kbyte = (ch & 3)*16;
    char* base = Aimg + (size_t)mb*(NSTEP1*16384) + (size_t)step*16384;
    int off = swzoff(row, kbyte);
    split_store(v, base + off, base + 8192 + off);
}

// ---------------------------------------------------------------------------
// MFMA GEMM (layer 1): C[128x128 tile] = bn_relu(A @ W). bf16 2-split.
// ---------------------------------------------------------------------------
__global__ __launch_bounds__(256,4) void gemm_mfma(
    const char* __restrict__ Aimg, const char* __restrict__ Wimg, int nstep,
    const float* __restrict__ bias,
    const float* __restrict__ gam, const float* __restrict__ bet,
    const float* __restrict__ mu,  const float* __restrict__ var,
    float* __restrict__ out)
{
    __shared__ uint4 lds4[34816/16];
    char* lds  = (char*)lds4;
    char* Alds = lds;
    char* Wlds = lds + 16384;
    float* scs = (float*)(lds + 32768);
    float* shs = scs + 256;
    const int tid = threadIdx.x;
    const int lane = tid & 63, wave = tid >> 6;
    const int wm = wave >> 1, wn = wave & 1;
    const int mblk = blockIdx.x, nblk = blockIdx.y;

    if (tid < 256) {
        float s = gam[tid] / sqrtf(var[tid] + 1e-5f);
        scs[tid] = s;
        shs[tid] = bet[tid] + (bias[tid] - mu[tid]) * s;
    }

    const char* Ab = Aimg + (size_t)mblk * nstep * 16384;
    const char* Wb = Wimg + (size_t)nblk * nstep * 16384;

    const char* gbase; char* lbase;
    int soff;
    if (wave < 2) { gbase = Ab;  lbase = Alds; soff = wave*8192; }
    else          { gbase = Wb;  lbase = Wlds; soff = (wave-2)*8192; }

    f32x4 acc[4][4];
    #pragma unroll
    for (int m = 0; m < 4; ++m)
        #pragma unroll
        for (int n = 0; n < 4; ++n) acc[m][n] = (f32x4){0.f,0.f,0.f,0.f};

    for (int s = 0; s < nstep; ++s) {
        #pragma unroll
        for (int i = 0; i < 8; ++i) {
            int off = soff + i*1024;
            __builtin_amdgcn_global_load_lds(
                (const __attribute__((address_space(1))) void*)(gbase + (size_t)s*16384 + off + lane*16),
                (__attribute__((address_space(3))) void*)(lbase + off), 16, 0, 0);
        }
        __syncthreads();
        const int kb = (lane >> 4) * 16;
        bf16x8 ah[4], al[4];
        #pragma unroll
        for (int m = 0; m < 4; ++m) {
            int row = wm*64 + m*16 + (lane & 15);
            int off = swzoff(row, kb);
            ah[m] = *(const bf16x8*)(Alds + off);
            al[m] = *(const bf16x8*)(Alds + 8192 + off);
        }
        #pragma unroll
        for (int n = 0; n < 4; ++n) {
            int col = wn*64 + n*16 + (lane & 15);
            int off = swzoff(col, kb);
            bf16x8 bh = *(const bf16x8*)(Wlds + off);
            bf16x8 bl = *(const bf16x8*)(Wlds + 8192 + off);
            #pragma unroll
            for (int m = 0; m < 4; ++m) {
                acc[m][n] = __builtin_amdgcn_mfma_f32_16x16x32_bf16(ah[m], bh, acc[m][n], 0, 0, 0);
                acc[m][n] = __builtin_amdgcn_mfma_f32_16x16x32_bf16(al[m], bh, acc[m][n], 0, 0, 0);
                acc[m][n] = __builtin_amdgcn_mfma_f32_16x16x32_bf16(ah[m], bl, acc[m][n], 0, 0, 0);
            }
        }
        __syncthreads();
    }

    #pragma unroll
    for (int n = 0; n < 4; ++n) {
        int c = nblk*128 + wn*64 + n*16 + (lane & 15);
        float sc = scs[c], sh = shs[c];
        #pragma unroll
        for (int m = 0; m < 4; ++m) {
            int r0 = mblk*128 + wm*64 + m*16 + (lane >> 4)*4;
            #pragma unroll
            for (int q = 0; q < 4; ++q) {
                float v = acc[m][n][q]*sc + sh;
                out[(size_t)(r0+q)*256 + c] = fmaxf(v, 0.f);
            }
        }
    }
}

// ---------------------------------------------------------------------------
// gcn_fused v5 (layers 2,3): h_out = relu(bn(agg(h_in) @ W + b)).
// HALF-COLUMN tiles: 64 rows x 128 cols, grid 2048 (bid&1 = col half).
// LDS 27 KB -> 4-5 blocks/CU; acc halved to 32 VGPR so the pf[14] gather
// prefetch fits under the launch_bounds(256,4) cap of 128 VGPR (real ILP).
// Layer-3 gate partials: atomicAdd of exactly 2 commutative contributions
// per node into zeroed gatep (bit-deterministic).
// ---------------------------------------------------------------------------
__global__ __launch_bounds__(256,4) void gcn_fused(
    const float* __restrict__ hin,
    const unsigned short* __restrict__ nbr,
    const char* __restrict__ Wimg,      // [2][8][hi 8KB | lo 8KB]
    const float* __restrict__ bias,
    const float* __restrict__ gam, const float* __restrict__ bet,
    const float* __restrict__ mu,  const float* __restrict__ var,
    float* __restrict__ hout,
    const float* __restrict__ gate_w, float* __restrict__ gatep)
{
    __shared__ uint4 lds4[27648/16];
    char* Alds = (char*)lds4;                    // 8 KB (hi 4K | lo 4K)
    char* Wlds = (char*)lds4 + 8192;             // 16 KB (hi 8K | lo 8K)
    float* scs = (float*)((char*)lds4 + 24576);  // 256 f
    float* shs = scs + 256;                      // 256 f
    float* gred = (float*)((char*)lds4 + 26624); // 256 f
    const int tid = threadIdx.x;
    const int lane = tid & 63, wave = tid >> 6;  // 4 waves
    const int wn = wave;
    const int bid = xcd_swz(blockIdx.x, gridDim.x);
    const int nb = bid & 1, mblk = bid >> 1;

    {
        float s = gam[tid] / sqrtf(var[tid] + 1e-5f);
        scs[tid] = s;
        shs[tid] = bet[tid] + (bias[tid] - mu[tid]) * s;
    }

    // per-thread A item: row = tid>>2 (0..63), chunk ch = tid&3 (8 feats)
    const int arow = tid >> 2, ch = tid & 3;
    const int gnode = mblk*64 + arow;
    const int gb = gnode & ~(NND-1);
    int jn[KNN];
    #pragma unroll
    for (int q = 0; q < KNN; ++q) jn[q] = gb + nbr[gnode*KNN + q];
    const float rs = 1.0f/sqrtf(7.0f);
    const float c1 = rs*rs, c2 = 1.0f/7.0f;
    const int aoff = swzoff(arow, ch*16);
    const float4* h4 = (const float4*)hin;
    const char* wbase = Wimg + (size_t)nb * 8 * 16384;

    f32x4 acc[4][2];
    #pragma unroll
    for (int m = 0; m < 4; ++m)
        #pragma unroll
        for (int n = 0; n < 2; ++n) acc[m][n] = (f32x4){0.f,0.f,0.f,0.f};

    float4 pf[14];
    // prefetch gather for step 0
    {
        const int fb = ch*2;
        #pragma unroll
        for (int q = 0; q < KNN; ++q) {
            pf[2*q]   = h4[(size_t)jn[q]*64 + fb];
            pf[2*q+1] = h4[(size_t)jn[q]*64 + fb + 1];
        }
        pf[12] = h4[(size_t)gnode*64 + fb];
        pf[13] = h4[(size_t)gnode*64 + fb + 1];
    }

    for (int s = 0; s < 8; ++s) {
        // (1) aggregate from prefetched regs, split, ds_write A(s)
        {
            float a0 = pf[0].x + pf[2].x + pf[4].x + pf[6].x + pf[8].x + pf[10].x;
            float a1 = pf[0].y + pf[2].y + pf[4].y + pf[6].y + pf[8].y + pf[10].y;
            float a2 = pf[0].z + pf[2].z + pf[4].z + pf[6].z + pf[8].z + pf[10].z;
            float a3 = pf[0].w + pf[2].w + pf[4].w + pf[6].w + pf[8].w + pf[10].w;
            float b0 = pf[1].x + pf[3].x + pf[5].x + pf[7].x + pf[9].x + pf[11].x;
            float b1 = pf[1].y + pf[3].y + pf[5].y + pf[7].y + pf[9].y + pf[11].y;
            float b2 = pf[1].z + pf[3].z + pf[5].z + pf[7].z + pf[9].z + pf[11].z;
            float b3 = pf[1].w + pf[3].w + pf[5].w + pf[7].w + pf[9].w + pf[11].w;
            float v[8];
            v[0]=a0*c1+pf[12].x*c2; v[1]=a1*c1+pf[12].y*c2;
            v[2]=a2*c1+pf[12].z*c2; v[3]=a3*c1+pf[12].w*c2;
            v[4]=b0*c1+pf[13].x*c2; v[5]=b1*c1+pf[13].y*c2;
            v[6]=b2*c1+pf[13].z*c2; v[7]=b3*c1+pf[13].w*c2;
            split_store(v, Alds + aoff, Alds + 4096 + aoff);
        }
        // (2) W stage: 16 KB (this column half), 4 issues/thread
        #pragma unroll
        for (int i = 0; i < 4; ++i) {
            int woff = i*4096 + wave*1024;
            __builtin_amdgcn_global_load_lds(
                (const __attribute__((address_space(1))) void*)(wbase + (size_t)s*16384 + woff + lane*16),
                (__attribute__((address_space(3))) void*)(Wlds + woff), 16, 0, 0);
        }
        __syncthreads();
        // (3) issue gather(s+1) -> rides under the MFMA phase
        if (s < 7) {
            const int fb = (s+1)*8 + ch*2;
            #pragma unroll
            for (int q = 0; q < KNN; ++q) {
                pf[2*q]   = h4[(size_t)jn[q]*64 + fb];
                pf[2*q+1] = h4[(size_t)jn[q]*64 + fb + 1];
            }
            pf[12] = h4[(size_t)gnode*64 + fb];
            pf[13] = h4[(size_t)gnode*64 + fb + 1];
        }
        // (4) MFMA(s)
        const int kb = (lane >> 4) * 16;
        bf16x8 ah[4], al[4];
        #pragma unroll
        for (int m = 0; m < 4; ++m) {
            int o = swzoff(m*16 + (lane & 15), kb);
            ah[m] = *(const bf16x8*)(Alds + o);
            al[m] = *(const bf16x8*)(Alds + 4096 + o);
        }
        #pragma unroll
        for (int n = 0; n < 2; ++n) {
            int cl = wn*32 + n*16 + (lane & 15);   // 0..127 within half
            int o = swzoff(cl, kb);
            bf16x8 bh = *(const bf16x8*)(Wlds + o);
            bf16x8 bl = *(const bf16x8*)(Wlds + 8192 + o);
            #pragma unroll
            for (int m = 0; m < 4; ++m) {
                acc[m][n] = __builtin_amdgcn_mfma_f32_16x16x32_bf16(ah[m], bh, acc[m][n], 0, 0, 0);
                acc[m][n] = __builtin_amdgcn_mfma_f32_16x16x32_bf16(al[m], bh, acc[m][n], 0, 0, 0);
                acc[m][n] = __builtin_amdgcn_mfma_f32_16x16x32_bf16(ah[m], bl, acc[m][n], 0, 0, 0);
            }
        }
        __syncthreads();
    }

    const bool dogate = (gatep != nullptr);
    float gp[4][4];
    #pragma unroll
    for (int m = 0; m < 4; ++m)
        #pragma unroll
        for (int q = 0; q < 4; ++q) gp[m][q] = 0.f;

    #pragma unroll
    for (int n = 0; n < 2; ++n) {
        int c = nb*128 + wn*32 + n*16 + (lane & 15);
        float sc = scs[c], sh = shs[c];
        float gwv = dogate ? gate_w[c] : 0.f;
        #pragma unroll
        for (int m = 0; m < 4; ++m) {
            int r0 = mblk*64 + m*16 + (lane >> 4)*4;
            #pragma unroll
            for (int q = 0; q < 4; ++q) {
                float v = fmaxf(acc[m][n][q]*sc + sh, 0.f);
                hout[(size_t)(r0+q)*256 + c] = v;
                gp[m][q] = fmaf(v, gwv, gp[m][q]);
            }
        }
    }

    if (dogate) {
        // butterfly over the 16-lane col group -> per-row wave partial
        #pragma unroll
        for (int m = 0; m < 4; ++m)
            #pragma unroll
            for (int q = 0; q < 4; ++q) {
                float s = gp[m][q];
                s += __shfl_xor(s, 1); s += __shfl_xor(s, 2);
                s += __shfl_xor(s, 4); s += __shfl_xor(s, 8);
                gp[m][q] = s;
            }
        if ((lane & 15) == 0) {
            #pragma unroll
            for (int m = 0; m < 4; ++m)
                #pragma unroll
                for (int q = 0; q < 4; ++q)
                    gred[wn*64 + m*16 + (lane >> 4)*4 + q] = gp[m][q];
        }
        __syncthreads();
        // sum 4 waves -> this block's 128-col partial; two halves combine
        // via atomicAdd (2 commutative float contributions: deterministic).
        if (tid < 64) {
            float v = (gred[tid] + gred[64 + tid])
                    + (gred[128 + tid] + gred[192 + tid]);
            atomicAdd(&gatep[mblk*64 + tid], v);
        }
    }
}

// ---------------------------------------------------------------------------
// Readout stage 1 (softmax folded): gembp[s][g][f]; gate from fused gatep.
// ---------------------------------------------------------------------------
__device__ __forceinline__ float blk_sum256(float v, volatile float* red)
{
    #pragma unroll
    for (int o = 32; o > 0; o >>= 1) v += __shfl_xor(v, o, 64);
    __syncthreads();
    if ((threadIdx.x & 63) == 0) red[threadIdx.x >> 6] = v;
    __syncthreads();
    return (red[0] + red[1]) + (red[2] + red[3]);
}

__global__ __launch_bounds__(256) void gemb_kernel(const float* __restrict__ h3,
                                                   const float* __restrict__ gatep,
                                                   const float* __restrict__ gate_b,
                                                   float* __restrict__ gembp)
{
    const int g = blockIdx.x, s = blockIdx.y;
    const int tid = threadIdx.x, lane = tid & 63, w = tid >> 6;
    __shared__ float at[128];
    __shared__ float red4[4][HF];
    __shared__ float red[4];

    float gb = gate_b[0];
    float g0 = fmaxf(gatep[g*NND + tid] + gb, 0.f);
    float g1 = fmaxf(gatep[g*NND + 256 + tid] + gb, 0.f);
    float m = fmaxf(g0, g1);
    #pragma unroll
    for (int o = 32; o > 0; o >>= 1) m = fmaxf(m, __shfl_xor(m, o, 64));
    if ((tid & 63) == 0) red[tid >> 6] = m;
    __syncthreads();
    m = fmaxf(fmaxf(red[0], red[1]), fmaxf(red[2], red[3]));
    float S = blk_sum256(expf(g0 - m) + expf(g1 - m), red);
    if (tid < 128) {
        float gv = fmaxf(gatep[g*NND + s*128 + tid] + gb, 0.f);
        at[tid] = expf(gv - m) / S;
    }
    __syncthreads();

    const float* hb = h3 + (size_t)(g*NND + s*128 + w*32) * HF;
    float4 acc = make_float4(0.f, 0.f, 0.f, 0.f);
    #pragma unroll 4
    for (int n = 0; n < 32; ++n) {
        float a = at[w*32 + n];
        float4 v = ((const float4*)(hb + (size_t)n*HF))[lane];
        acc.x = fmaf(a, v.x, acc.x); acc.y = fmaf(a, v.y, acc.y);
        acc.z = fmaf(a, v.z, acc.z); acc.w = fmaf(a, v.w, acc.w);
    }
    *(float4*)&red4[w][lane*4] = acc;
    __syncthreads();
    if (tid < HF) {
        float sum = (red4[0][tid] + red4[1][tid]) + (red4[2][tid] + red4[3][tid]);
        gembp[((size_t)s*NBG + g)*HF + tid] = sum;
    }
}

// ---------------------------------------------------------------------------
// Readout stage 2: heads.
// ---------------------------------------------------------------------------
__global__ __launch_bounds__(256) void heads_kernel(
    const float* __restrict__ gembp,
    const float* __restrict__ aff_w,  const float* __restrict__ aff_b,
    const float* __restrict__ rl_w1,  const float* __restrict__ rl_b1,
    const float* __restrict__ rl_w2,  const float* __restrict__ rl_b2,
    float* __restrict__ out)
{
    int g = blockIdx.x, tid = threadIdx.x;
    __shared__ float gemb[HF];
    __shared__ float red[4];
    float acc = (gembp[((size_t)0*NBG + g)*HF + tid] + gembp[((size_t)1*NBG + g)*HF + tid])
              + (gembp[((size_t)2*NBG + g)*HF + tid] + gembp[((size_t)3*NBG + g)*HF + tid]);
    gemb[tid] = acc;
    __syncthreads();

    float sa = blk_sum256(acc * aff_w[tid], red);
    if (tid == 0) out[g] = sa + aff_b[0];

    float t = rl_b1[tid];
    #pragma unroll 4
    for (int k2 = 0; k2 < HF; ++k2)
        t = fmaf(gemb[k2], rl_w1[(size_t)k2*HF + tid], t);
    t = fmaxf(t, 0.f);
    float s0 = blk_sum256(t * rl_w2[(size_t)tid*3 + 0], red);
    if (tid == 0) out[128 + g*3 + 0] = s0 + rl_b2[0];
    float s1 = blk_sum256(t * rl_w2[(size_t)tid*3 + 1], red);
    if (tid == 0) out[128 + g*3 + 1] = s1 + rl_b2[1];
    float s2 = blk_sum256(t * rl_w2[(size_t)tid*3 + 2], red);
    if (tid == 0) out[128 + g*3 + 2] = s2 + rl_b2[2];
}

// ---------------------------------------------------------------------------
extern "C" void kernel_launch(void* const* d_in, const int* in_sizes, int n_in,
                              void* d_out, int out_size, void* d_ws, size_t ws_size,
                              hipStream_t stream)
{
    const float* x      = (const float*)d_in[0];
    const float* pos    = (const float*)d_in[1];
    const float* W1     = (const float*)d_in[2];
    const float* b1     = (const float*)d_in[3];
    const float* W2     = (const float*)d_in[4];
    const float* b2     = (const float*)d_in[5];
    const float* W3     = (const float*)d_in[6];
    const float* b3     = (const float*)d_in[7];
    const float* g1     = (const float*)d_in[8];
    const float* be1    = (const float*)d_in[9];
    const float* m1     = (const float*)d_in[10];
    const float* v1     = (const float*)d_in[11];
    const float* g2     = (const float*)d_in[12];
    const float* be2    = (const float*)d_in[13];
    const float* m2     = (const float*)d_in[14];
    const float* v2     = (const float*)d_in[15];
    const float* g3     = (const float*)d_in[16];
    const float* be3    = (const float*)d_in[17];
    const float* m3     = (const float*)d_in[18];
    const float* v3     = (const float*)d_in[19];
    const float* gate_w = (const float*)d_in[20];
    const float* gate_b = (const float*)d_in[21];
    const float* aff_w  = (const float*)d_in[22];
    const float* aff_b  = (const float*)d_in[23];
    const float* rl_w1  = (const float*)d_in[24];
    const float* rl_b1  = (const float*)d_in[25];
    const float* rl_w2  = (const float*)d_in[26];
    const float* rl_b2  = (const float*)d_in[27];
    float* out = (float*)d_out;

    // workspace layout (~135.7 MB extent, unchanged)
    char* wsb = (char*)d_ws;
    unsigned short* nbr = (unsigned short*)wsb;               // 786,432 B
    char* Wimg1 = wsb + 786432;                               // 163,840 B
    char* Wimg2 = Wimg1 + (size_t)2*NSTEP1*16384;             // 262,144 B
    char* Wimg3 = Wimg2 + (size_t)2*8*16384;                  // 262,144 B
    float* h_a  = (float*)(Wimg3 + (size_t)2*8*16384);        // 67.1 MB
    char* regB  = (char*)(h_a + (size_t)NB_TOT*HF);           // 67.1 MB
    // gatep (256 KB = NB_TOT*4, exact fit) aliases Wimg2: dead after the
    // layer-2 gcn_fused reads it; zeroed by memset before layer-3 writes.
    float* gatep = (float*)Wimg2;
    // region B: agg_first's Aimg -> gemm1 reads -> h_b overwrites ->
    // layer3 reads h_b -> gembp overwrites in readout.
    char*  Aimg  = regB;
    float* h_b   = (float*)regB;
    float* gembp = (float*)regB;

    knn_kernel<<<NBG*8, 256, 0, stream>>>(pos, nbr);
    prew_all<<<84, 256, 0, stream>>>(W1, W2, W3, Wimg1, Wimg2, Wimg3);

    agg_first<<<(NB_TOT*20)/256, 256, 0, stream>>>(x, pos, nbr, Aimg);
    gemm_mfma<<<dim3(NB_TOT/128, 2), 256, 0, stream>>>(Aimg, Wimg1, NSTEP1,
        b1, g1, be1, m1, v1, h_a);
    gcn_fused<<<(NB_TOT/64)*2, 256, 0, stream>>>(h_a, nbr, Wimg2,
        b2, g2, be2, m2, v2, h_b, gate_w, nullptr);
    hipMemsetAsync(gatep, 0, (size_t)NB_TOT*4, stream);
    gcn_fused<<<(NB_TOT/64)*2, 256, 0, stream>>>(h_b, nbr, Wimg3,
        b3, g3, be3, m3, v3, h_a, gate_w, gatep);

    gemb_kernel<<<dim3(NBG, 4), 256, 0, stream>>>(h_a, gatep, gate_b, gembp);
    heads_kernel<<<NBG, 256, 0, stream>>>(gembp, aff_w, aff_b,
                                          rl_w1, rl_b1, rl_w2, rl_b2, out);
}

// Round 19
// 210.700 us; speedup vs baseline: 1.0961x; 1.0961x over previous
//
#include <hip/hip_runtime.h>
#include <hip/hip_bf16.h>
#include <math.h>
#include <float.h>

#define NBG 128      // graphs
#define NND 512      // nodes per graph
#define KNN 6
#define NB_TOT (NBG*NND)
#define HF 256
#define NSTEP1 5     // layer-1 K padded to 160 (131 real)

typedef short bf16x8 __attribute__((ext_vector_type(8)));
typedef float f32x4 __attribute__((ext_vector_type(4)));

// byte offset of element (row, kbyte) in a [rows][32 k] bf16 plane,
// XOR-swizzled so 16-lane frag reads cover all eight 16-B slots (2-way free).
__device__ __forceinline__ int swzoff(int row, int kbyte) {
    return (row*64 + kbyte) ^ (((row>>1)&3)<<4);
}

__device__ __forceinline__ void split_store(const float* v, char* hi_p, char* lo_p) {
    bf16x8 hi, lo;
    #pragma unroll
    for (int j = 0; j < 8; ++j) {
        __hip_bfloat16 h = __float2bfloat16(v[j]);
        float hf = __bfloat162float(h);
        __hip_bfloat16 l = __float2bfloat16(v[j] - hf);
        hi[j] = *(short*)&h;
        lo[j] = *(short*)&l;
    }
    *(bf16x8*)hi_p = hi;
    *(bf16x8*)lo_p = lo;
}

// XCD-aware bijective block swizzle (grid must be a multiple of 8).
__device__ __forceinline__ int xcd_swz(int bid, int grid) {
    return (bid & 7) * (grid >> 3) + (bid >> 3);
}

// ---------------------------------------------------------------------------
// kNN v4b (proven 47 us): 8 blocks/graph, 4 lanes/node, 128 candidates/lane
// as 2 independent branchless (d2,idx) chains.
// ---------------------------------------------------------------------------
__global__ __launch_bounds__(256) void knn_kernel(const float* __restrict__ pos,
                                                  unsigned short* __restrict__ nbr)
{
    const int blk = blockIdx.x;           // 1024 blocks
    const int g = blk >> 3;
    const int chunk = (blk & 7) * 64;
    const int tid = threadIdx.x;
    const int node = chunk + (tid >> 2);  // local node id
    const int sub = tid & 3;

    __shared__ float4 p4[NND + (NND>>6)]; // padded: idx j -> j + (j>>6)
    const float* pg = pos + (size_t)g * NND * 3;
    for (int n = tid; n < NND; n += 256) {
        float x = pg[n*3+0], y = pg[n*3+1], z = pg[n*3+2];
        p4[n + (n>>6)] = make_float4(x, y, z, x*x + y*y + z*z);
    }
    __syncthreads();

    const float4 pi = p4[node + (node>>6)];
    const float m2x = -2.0f*pi.x, m2y = -2.0f*pi.y, m2z = -2.0f*pi.z;

    float bdA[KNN], bdB[KNN]; int biA[KNN], biB[KNN];
    #pragma unroll
    for (int q = 0; q < KNN; ++q) {
        bdA[q] = FLT_MAX; biA[q] = 0x7fffffff;
        bdB[q] = FLT_MAX; biB[q] = 0x7fffffff;
    }

    const int j0 = sub * 128;
    const float4* baseA = &p4[sub*130];
    const float4* baseB = &p4[sub*130 + 65];

    #pragma unroll 2
    for (int t = 0; t < 64; ++t) {
        int ja = j0 + t, jb = j0 + 64 + t;
        float4 pa = baseA[t];
        float4 pb = baseB[t];
        float da = fmaf(m2z, pa.z, fmaf(m2y, pa.y, fmaf(m2x, pa.x, pa.w)));
        float db = fmaf(m2z, pb.z, fmaf(m2y, pb.y, fmaf(m2x, pb.x, pb.w)));
        da = (ja == node) ? FLT_MAX : da;
        db = (jb == node) ? FLT_MAX : db;
        float ca = da; int ia = ja;
        float cb = db; int ib = jb;
        #pragma unroll
        for (int q = 0; q < KNN; ++q) {
            bool sa = ca < bdA[q];
            float t1 = sa ? ca : bdA[q]; float t2 = sa ? bdA[q] : ca;
            int   t3 = sa ? ia : biA[q]; int   t4 = sa ? biA[q] : ia;
            bdA[q] = t1; ca = t2; biA[q] = t3; ia = t4;
            bool sb = cb < bdB[q];
            float u1 = sb ? cb : bdB[q]; float u2 = sb ? bdB[q] : cb;
            int   u3 = sb ? ib : biB[q]; int   u4 = sb ? biB[q] : ib;
            bdB[q] = u1; cb = u2; biB[q] = u3; ib = u4;
        }
    }

    // local merge of chains A and B (min-trick + bubble sort network)
    float ld[KNN]; int li[KNN];
    #pragma unroll
    for (int q = 0; q < KNN; ++q) {
        float ad = bdA[q], xd = bdB[KNN-1-q];
        int   ai = biA[q], xi = biB[KNN-1-q];
        bool t = (ad < xd) || (ad == xd && ai < xi);
        ld[q] = t ? ad : xd;
        li[q] = t ? ai : xi;
    }
    #pragma unroll
    for (int pass = 0; pass < KNN-1; ++pass)
        #pragma unroll
        for (int a = 0; a < KNN-1-pass; ++a) {
            int b = a+1;
            bool sw = (ld[b] < ld[a]) || (ld[b] == ld[a] && li[b] < li[a]);
            float td = sw ? ld[b] : ld[a]; float ud = sw ? ld[a] : ld[b];
            int   ti = sw ? li[b] : li[a]; int   ui = sw ? li[a] : li[b];
            ld[a] = td; li[a] = ti; ld[b] = ud; li[b] = ui;
        }

    // cross-lane merges: partner masks 1 then 2 (4 lanes per node)
    #pragma unroll
    for (int mi = 0; mi < 2; ++mi) {
        const int mask = 1 << mi;
        float od[KNN]; int oi[KNN];
        #pragma unroll
        for (int q = 0; q < KNN; ++q) {
            od[q] = __shfl_xor(ld[q], mask);
            oi[q] = __shfl_xor(li[q], mask);
        }
        #pragma unroll
        for (int q = 0; q < KNN; ++q) {
            float ad = ld[q], xd = od[KNN-1-q];
            int   ai = li[q], xi = oi[KNN-1-q];
            bool t = (ad < xd) || (ad == xd && ai < xi);
            ld[q] = t ? ad : xd;
            li[q] = t ? ai : xi;
        }
        #pragma unroll
        for (int pass = 0; pass < KNN-1; ++pass)
            #pragma unroll
            for (int a = 0; a < KNN-1-pass; ++a) {
                int b = a+1;
                bool sw = (ld[b] < ld[a]) || (ld[b] == ld[a] && li[b] < li[a]);
                float td = sw ? ld[b] : ld[a]; float ud = sw ? ld[a] : ld[b];
                int   ti = sw ? li[b] : li[a]; int   ui = sw ? li[a] : li[b];
                ld[a] = td; li[a] = ti; ld[b] = ud; li[b] = ui;
            }
    }

    if (sub == 0) {
        int base = (g*NND + node)*KNN;
        #pragma unroll
        for (int q = 0; q < KNN; ++q) nbr[base+q] = (unsigned short)li[q];
    }
}

// ---------------------------------------------------------------------------
// W pre-pass (all 3 layers fused): build swizzled hi/lo bf16 images of W.
// ---------------------------------------------------------------------------
__global__ __launch_bounds__(256) void prew_all(
    const float* __restrict__ W1, const float* __restrict__ W2,
    const float* __restrict__ W3,
    char* __restrict__ I1, char* __restrict__ I2, char* __restrict__ I3)
{
    int b = blockIdx.x;
    const float* W; char* img; int K, nstep;
    if (b < 20)      { W = W1; img = I1; K = 131; nstep = 5; }
    else if (b < 52) { W = W2; img = I2; K = 256; nstep = 8; b -= 20; }
    else             { W = W3; img = I3; K = 256; nstep = 8; b -= 52; }
    int gid = b*256 + threadIdx.x;
    int per_nb = nstep*512;
    int nb = gid / per_nb;
    int r  = gid - nb*per_nb;
    int step = r >> 9;
    int r2 = r & 511;
    int cl = r2 >> 2;
    int kc = (r2 & 3) * 8;
    float v[8];
    #pragma unroll
    for (int j = 0; j < 8; ++j) {
        int gk = step*32 + kc + j;
        v[j] = (gk < K) ? W[(size_t)gk*256 + nb*128 + cl] : 0.f;
    }
    char* base = img + (size_t)nb*nstep*16384 + (size_t)step*16384;
    int off = swzoff(cl, kc*2);
    split_store(v, base + off, base + 8192 + off);
}

// ---------------------------------------------------------------------------
// agg_first: A1 image from concat(x,pos). XCD-swizzled blocks.
// ---------------------------------------------------------------------------
__global__ __launch_bounds__(256) void agg_first(const float* __restrict__ x,
                                                 const float* __restrict__ pos,
                                                 const unsigned short* __restrict__ nbr,
                                                 char* __restrict__ Aimg)
{
    int gid = xcd_swz(blockIdx.x, gridDim.x)*256 + threadIdx.x;   // NB_TOT*20
    int i = gid / 20, ch = gid - i*20;
    const float rs = 1.0f/sqrtf(7.0f);
    const float c1 = rs*rs, c2 = 1.0f/7.0f;
    const int gbase = i & ~(NND-1);
    float v[8];
    if (ch < 16) {
        int jn[KNN];
        #pragma unroll
        for (int q = 0; q < KNN; ++q) jn[q] = gbase + nbr[i*KNN+q];
        const float4* x4 = (const float4*)x;
        int c4 = ch*2;
        float4 s0 = x4[(size_t)i*32 + c4], s1 = x4[(size_t)i*32 + c4 + 1];
        float a0=0,a1=0,a2=0,a3=0,b0=0,b1=0,b2=0,b3=0;
        #pragma unroll
        for (int q = 0; q < KNN; ++q) {
            float4 t0 = x4[(size_t)jn[q]*32 + c4];
            float4 t1 = x4[(size_t)jn[q]*32 + c4 + 1];
            a0+=t0.x; a1+=t0.y; a2+=t0.z; a3+=t0.w;
            b0+=t1.x; b1+=t1.y; b2+=t1.z; b3+=t1.w;
        }
        v[0]=a0*c1+s0.x*c2; v[1]=a1*c1+s0.y*c2; v[2]=a2*c1+s0.z*c2; v[3]=a3*c1+s0.w*c2;
        v[4]=b0*c1+s1.x*c2; v[5]=b1*c1+s1.y*c2; v[6]=b2*c1+s1.z*c2; v[7]=b3*c1+s1.w*c2;
    } else if (ch == 16) {
        int jn[KNN];
        #pragma unroll
        for (int q = 0; q < KNN; ++q) jn[q] = gbase + nbr[i*KNN+q];
        float ax=0, ay=0, az=0;
        #pragma unroll
        for (int q = 0; q < KNN; ++q) {
            ax += pos[(size_t)jn[q]*3+0];
            ay += pos[(size_t)jn[q]*3+1];
            az += pos[(size_t)jn[q]*3+2];
        }
        v[0] = ax*c1 + pos[(size_t)i*3+0]*c2;
        v[1] = ay*c1 + pos[(size_t)i*3+1]*c2;
        v[2] = az*c1 + pos[(size_t)i*3+2]*c2;
        v[3]=v[4]=v[5]=v[6]=v[7]=0.f;
    } else {
        #pragma unroll
        for (int j = 0; j < 8; ++j) v[j] = 0.f;
    }
    int mb = i >> 7, row = i & 127, step = ch >> 2, kbyte = (ch & 3)*16;
    char* base = Aimg + (size_t)mb*(NSTEP1*16384) + (size_t)step*16384;
    int off = swzoff(row, kbyte);
    split_store(v, base + off, base + 8192 + off);
}

// ---------------------------------------------------------------------------
// MFMA GEMM (layer 1): C[128x128 tile] = bn_relu(A @ W). bf16 2-split.
// ---------------------------------------------------------------------------
__global__ __launch_bounds__(256,4) void gemm_mfma(
    const char* __restrict__ Aimg, const char* __restrict__ Wimg, int nstep,
    const float* __restrict__ bias,
    const float* __restrict__ gam, const float* __restrict__ bet,
    const float* __restrict__ mu,  const float* __restrict__ var,
    float* __restrict__ out)
{
    __shared__ uint4 lds4[34816/16];
    char* lds  = (char*)lds4;
    char* Alds = lds;
    char* Wlds = lds + 16384;
    float* scs = (float*)(lds + 32768);
    float* shs = scs + 256;
    const int tid = threadIdx.x;
    const int lane = tid & 63, wave = tid >> 6;
    const int wm = wave >> 1, wn = wave & 1;
    const int mblk = blockIdx.x, nblk = blockIdx.y;

    if (tid < 256) {
        float s = gam[tid] / sqrtf(var[tid] + 1e-5f);
        scs[tid] = s;
        shs[tid] = bet[tid] + (bias[tid] - mu[tid]) * s;
    }

    const char* Ab = Aimg + (size_t)mblk * nstep * 16384;
    const char* Wb = Wimg + (size_t)nblk * nstep * 16384;

    const char* gbase; char* lbase;
    int soff;
    if (wave < 2) { gbase = Ab;  lbase = Alds; soff = wave*8192; }
    else          { gbase = Wb;  lbase = Wlds; soff = (wave-2)*8192; }

    f32x4 acc[4][4];
    #pragma unroll
    for (int m = 0; m < 4; ++m)
        #pragma unroll
        for (int n = 0; n < 4; ++n) acc[m][n] = (f32x4){0.f,0.f,0.f,0.f};

    for (int s = 0; s < nstep; ++s) {
        #pragma unroll
        for (int i = 0; i < 8; ++i) {
            int off = soff + i*1024;
            __builtin_amdgcn_global_load_lds(
                (const __attribute__((address_space(1))) void*)(gbase + (size_t)s*16384 + off + lane*16),
                (__attribute__((address_space(3))) void*)(lbase + off), 16, 0, 0);
        }
        __syncthreads();
        const int kb = (lane >> 4) * 16;
        bf16x8 ah[4], al[4];
        #pragma unroll
        for (int m = 0; m < 4; ++m) {
            int row = wm*64 + m*16 + (lane & 15);
            int off = swzoff(row, kb);
            ah[m] = *(const bf16x8*)(Alds + off);
            al[m] = *(const bf16x8*)(Alds + 8192 + off);
        }
        #pragma unroll
        for (int n = 0; n < 4; ++n) {
            int col = wn*64 + n*16 + (lane & 15);
            int off = swzoff(col, kb);
            bf16x8 bh = *(const bf16x8*)(Wlds + off);
            bf16x8 bl = *(const bf16x8*)(Wlds + 8192 + off);
            #pragma unroll
            for (int m = 0; m < 4; ++m) {
                acc[m][n] = __builtin_amdgcn_mfma_f32_16x16x32_bf16(ah[m], bh, acc[m][n], 0, 0, 0);
                acc[m][n] = __builtin_amdgcn_mfma_f32_16x16x32_bf16(al[m], bh, acc[m][n], 0, 0, 0);
                acc[m][n] = __builtin_amdgcn_mfma_f32_16x16x32_bf16(ah[m], bl, acc[m][n], 0, 0, 0);
            }
        }
        __syncthreads();
    }

    #pragma unroll
    for (int n = 0; n < 4; ++n) {
        int c = nblk*128 + wn*64 + n*16 + (lane & 15);
        float sc = scs[c], sh = shs[c];
        #pragma unroll
        for (int m = 0; m < 4; ++m) {
            int r0 = mblk*128 + wm*64 + m*16 + (lane >> 4)*4;
            #pragma unroll
            for (int q = 0; q < 4; ++q) {
                float v = acc[m][n][q]*sc + sh;
                out[(size_t)(r0+q)*256 + c] = fmaxf(v, 0.f);
            }
        }
    }
}

// ---------------------------------------------------------------------------
// gcn_fused v2+gate (layers 2,3): h_out = relu(bn(agg(h_in) @ W + b)).
// 256 threads = 4 waves (1m x 4n), tile 64x256, grid 1024, XCD-swizzled.
// Gather register-prefetched one K-step ahead (proven structure).
// Layer 3 additionally emits gatep[row] = h_out[row]·gate_w (full 256-col
// dot per block: butterfly over 16-lane col group + LDS cross-wave reduce).
// ---------------------------------------------------------------------------
__global__ __launch_bounds__(256,3) void gcn_fused(
    const float* __restrict__ hin,
    const unsigned short* __restrict__ nbr,
    const char* __restrict__ Wimg,      // [2][8][16KB]
    const float* __restrict__ bias,
    const float* __restrict__ gam, const float* __restrict__ bet,
    const float* __restrict__ mu,  const float* __restrict__ var,
    float* __restrict__ hout,
    const float* __restrict__ gate_w, float* __restrict__ gatep)
{
    __shared__ uint4 lds4[44032/16];
    char* Alds = (char*)lds4;                    // 8 KB (hi 4K | lo 4K)
    char* Wlds = (char*)lds4 + 8192;             // 32 KB
    float* scs = (float*)((char*)lds4 + 40960);  // 256 f
    float* shs = scs + 256;                      // 256 f
    float* gred = (float*)((char*)lds4 + 43008); // 256 f
    const int tid = threadIdx.x;
    const int lane = tid & 63, wave = tid >> 6;  // 4 waves
    const int wn = wave;
    const int mblk = xcd_swz(blockIdx.x, gridDim.x);

    {
        float s = gam[tid] / sqrtf(var[tid] + 1e-5f);
        scs[tid] = s;
        shs[tid] = bet[tid] + (bias[tid] - mu[tid]) * s;
    }

    // per-thread A item: row = tid>>2 (0..63), chunk ch = tid&3 (8 feats)
    const int arow = tid >> 2, ch = tid & 3;
    const int gnode = mblk*64 + arow;
    const int gb = gnode & ~(NND-1);
    int jn[KNN];
    #pragma unroll
    for (int q = 0; q < KNN; ++q) jn[q] = gb + nbr[gnode*KNN + q];
    const float rs = 1.0f/sqrtf(7.0f);
    const float c1 = rs*rs, c2 = 1.0f/7.0f;
    const int aoff = swzoff(arow, ch*16);
    const float4* h4 = (const float4*)hin;

    f32x4 acc[4][4];
    #pragma unroll
    for (int m = 0; m < 4; ++m)
        #pragma unroll
        for (int n = 0; n < 4; ++n) acc[m][n] = (f32x4){0.f,0.f,0.f,0.f};

    float4 pf[14];
    // prefetch gather for step 0
    {
        const int fb = ch*2;
        #pragma unroll
        for (int q = 0; q < KNN; ++q) {
            pf[2*q]   = h4[(size_t)jn[q]*64 + fb];
            pf[2*q+1] = h4[(size_t)jn[q]*64 + fb + 1];
        }
        pf[12] = h4[(size_t)gnode*64 + fb];
        pf[13] = h4[(size_t)gnode*64 + fb + 1];
    }

    for (int s = 0; s < 8; ++s) {
        // (1) aggregate from prefetched regs, split, ds_write A(s)
        {
            float a0 = pf[0].x + pf[2].x + pf[4].x + pf[6].x + pf[8].x + pf[10].x;
            float a1 = pf[0].y + pf[2].y + pf[4].y + pf[6].y + pf[8].y + pf[10].y;
            float a2 = pf[0].z + pf[2].z + pf[4].z + pf[6].z + pf[8].z + pf[10].z;
            float a3 = pf[0].w + pf[2].w + pf[4].w + pf[6].w + pf[8].w + pf[10].w;
            float b0 = pf[1].x + pf[3].x + pf[5].x + pf[7].x + pf[9].x + pf[11].x;
            float b1 = pf[1].y + pf[3].y + pf[5].y + pf[7].y + pf[9].y + pf[11].y;
            float b2 = pf[1].z + pf[3].z + pf[5].z + pf[7].z + pf[9].z + pf[11].z;
            float b3 = pf[1].w + pf[3].w + pf[5].w + pf[7].w + pf[9].w + pf[11].w;
            float v[8];
            v[0]=a0*c1+pf[12].x*c2; v[1]=a1*c1+pf[12].y*c2;
            v[2]=a2*c1+pf[12].z*c2; v[3]=a3*c1+pf[12].w*c2;
            v[4]=b0*c1+pf[13].x*c2; v[5]=b1*c1+pf[13].y*c2;
            v[6]=b2*c1+pf[13].z*c2; v[7]=b3*c1+pf[13].w*c2;
            split_store(v, Alds + aoff, Alds + 4096 + aoff);
        }
        // W stage: 32 KB = [nb0 hi|lo 16KB][nb1 hi|lo 16KB]
        #pragma unroll
        for (int i = 0; i < 8; ++i) {
            int woff = i*4096 + wave*1024;
            size_t srcoff = (woff < 16384) ? ((size_t)s*16384 + woff)
                                           : ((size_t)(8+s)*16384 + (woff - 16384));
            __builtin_amdgcn_global_load_lds(
                (const __attribute__((address_space(1))) void*)(Wimg + srcoff + lane*16),
                (__attribute__((address_space(3))) void*)(Wlds + woff), 16, 0, 0);
        }
        __syncthreads();
        // (3) issue gather(s+1) -> rides under the MFMA phase
        if (s < 7) {
            const int fb = (s+1)*8 + ch*2;
            #pragma unroll
            for (int q = 0; q < KNN; ++q) {
                pf[2*q]   = h4[(size_t)jn[q]*64 + fb];
                pf[2*q+1] = h4[(size_t)jn[q]*64 + fb + 1];
            }
            pf[12] = h4[(size_t)gnode*64 + fb];
            pf[13] = h4[(size_t)gnode*64 + fb + 1];
        }
        // (4) MFMA(s)
        const int kb = (lane >> 4) * 16;
        bf16x8 ah[4], al[4];
        #pragma unroll
        for (int m = 0; m < 4; ++m) {
            int o = swzoff(m*16 + (lane & 15), kb);
            ah[m] = *(const bf16x8*)(Alds + o);
            al[m] = *(const bf16x8*)(Alds + 4096 + o);
        }
        const char* wreg = Wlds + (wn >> 1)*16384;
        #pragma unroll
        for (int n = 0; n < 4; ++n) {
            int cl = (wn & 1)*64 + n*16 + (lane & 15);   // col & 127
            int o = swzoff(cl, kb);
            bf16x8 bh = *(const bf16x8*)(wreg + o);
            bf16x8 bl = *(const bf16x8*)(wreg + 8192 + o);
            #pragma unroll
            for (int m = 0; m < 4; ++m) {
                acc[m][n] = __builtin_amdgcn_mfma_f32_16x16x32_bf16(ah[m], bh, acc[m][n], 0, 0, 0);
                acc[m][n] = __builtin_amdgcn_mfma_f32_16x16x32_bf16(al[m], bh, acc[m][n], 0, 0, 0);
                acc[m][n] = __builtin_amdgcn_mfma_f32_16x16x32_bf16(ah[m], bl, acc[m][n], 0, 0, 0);
            }
        }
        __syncthreads();
    }

    const bool dogate = (gatep != nullptr);
    float gp[4][4];
    #pragma unroll
    for (int m = 0; m < 4; ++m)
        #pragma unroll
        for (int q = 0; q < 4; ++q) gp[m][q] = 0.f;

    #pragma unroll
    for (int n = 0; n < 4; ++n) {
        int c = wn*64 + n*16 + (lane & 15);
        float sc = scs[c], sh = shs[c];
        float gwv = dogate ? gate_w[c] : 0.f;
        #pragma unroll
        for (int m = 0; m < 4; ++m) {
            int r0 = mblk*64 + m*16 + (lane >> 4)*4;
            #pragma unroll
            for (int q = 0; q < 4; ++q) {
                float v = fmaxf(acc[m][n][q]*sc + sh, 0.f);
                hout[(size_t)(r0+q)*256 + c] = v;
                gp[m][q] = fmaf(v, gwv, gp[m][q]);
            }
        }
    }

    if (dogate) {
        // butterfly over the 16-lane col group -> per-row wave partial
        #pragma unroll
        for (int m = 0; m < 4; ++m)
            #pragma unroll
            for (int q = 0; q < 4; ++q) {
                float s = gp[m][q];
                s += __shfl_xor(s, 1); s += __shfl_xor(s, 2);
                s += __shfl_xor(s, 4); s += __shfl_xor(s, 8);
                gp[m][q] = s;
            }
        if ((lane & 15) == 0) {
            #pragma unroll
            for (int m = 0; m < 4; ++m)
                #pragma unroll
                for (int q = 0; q < 4; ++q)
                    gred[wn*64 + m*16 + (lane >> 4)*4 + q] = gp[m][q];
        }
        __syncthreads();
        if (tid < 64)
            gatep[mblk*64 + tid] = (gred[tid] + gred[64 + tid])
                                 + (gred[128 + tid] + gred[192 + tid]);
    }
}

// ---------------------------------------------------------------------------
// Readout stage 1 (softmax folded): gembp[s][g][f]; gate from fused gatep.
// ---------------------------------------------------------------------------
__device__ __forceinline__ float blk_sum256(float v, volatile float* red)
{
    #pragma unroll
    for (int o = 32; o > 0; o >>= 1) v += __shfl_xor(v, o, 64);
    __syncthreads();
    if ((threadIdx.x & 63) == 0) red[threadIdx.x >> 6] = v;
    __syncthreads();
    return (red[0] + red[1]) + (red[2] + red[3]);
}

__global__ __launch_bounds__(256) void gemb_kernel(const float* __restrict__ h3,
                                                   const float* __restrict__ gatep,
                                                   const float* __restrict__ gate_b,
                                                   float* __restrict__ gembp)
{
    const int g = blockIdx.x, s = blockIdx.y;
    const int tid = threadIdx.x, lane = tid & 63, w = tid >> 6;
    __shared__ float at[128];
    __shared__ float red4[4][HF];
    __shared__ float red[4];

    float gb = gate_b[0];
    float g0 = fmaxf(gatep[g*NND + tid] + gb, 0.f);
    float g1 = fmaxf(gatep[g*NND + 256 + tid] + gb, 0.f);
    float m = fmaxf(g0, g1);
    #pragma unroll
    for (int o = 32; o > 0; o >>= 1) m = fmaxf(m, __shfl_xor(m, o, 64));
    if ((tid & 63) == 0) red[tid >> 6] = m;
    __syncthreads();
    m = fmaxf(fmaxf(red[0], red[1]), fmaxf(red[2], red[3]));
    float S = blk_sum256(expf(g0 - m) + expf(g1 - m), red);
    if (tid < 128) {
        float gv = fmaxf(gatep[g*NND + s*128 + tid] + gb, 0.f);
        at[tid] = expf(gv - m) / S;
    }
    __syncthreads();

    const float* hb = h3 + (size_t)(g*NND + s*128 + w*32) * HF;
    float4 acc = make_float4(0.f, 0.f, 0.f, 0.f);
    #pragma unroll 4
    for (int n = 0; n < 32; ++n) {
        float a = at[w*32 + n];
        float4 v = ((const float4*)(hb + (size_t)n*HF))[lane];
        acc.x = fmaf(a, v.x, acc.x); acc.y = fmaf(a, v.y, acc.y);
        acc.z = fmaf(a, v.z, acc.z); acc.w = fmaf(a, v.w, acc.w);
    }
    *(float4*)&red4[w][lane*4] = acc;
    __syncthreads();
    if (tid < HF) {
        float sum = (red4[0][tid] + red4[1][tid]) + (red4[2][tid] + red4[3][tid]);
        gembp[((size_t)s*NBG + g)*HF + tid] = sum;
    }
}

// ---------------------------------------------------------------------------
// Readout stage 2: heads.
// ---------------------------------------------------------------------------
__global__ __launch_bounds__(256) void heads_kernel(
    const float* __restrict__ gembp,
    const float* __restrict__ aff_w,  const float* __restrict__ aff_b,
    const float* __restrict__ rl_w1,  const float* __restrict__ rl_b1,
    const float* __restrict__ rl_w2,  const float* __restrict__ rl_b2,
    float* __restrict__ out)
{
    int g = blockIdx.x, tid = threadIdx.x;
    __shared__ float gemb[HF];
    __shared__ float red[4];
    float acc = (gembp[((size_t)0*NBG + g)*HF + tid] + gembp[((size_t)1*NBG + g)*HF + tid])
              + (gembp[((size_t)2*NBG + g)*HF + tid] + gembp[((size_t)3*NBG + g)*HF + tid]);
    gemb[tid] = acc;
    __syncthreads();

    float sa = blk_sum256(acc * aff_w[tid], red);
    if (tid == 0) out[g] = sa + aff_b[0];

    float t = rl_b1[tid];
    #pragma unroll 4
    for (int k2 = 0; k2 < HF; ++k2)
        t = fmaf(gemb[k2], rl_w1[(size_t)k2*HF + tid], t);
    t = fmaxf(t, 0.f);
    float s0 = blk_sum256(t * rl_w2[(size_t)tid*3 + 0], red);
    if (tid == 0) out[128 + g*3 + 0] = s0 + rl_b2[0];
    float s1 = blk_sum256(t * rl_w2[(size_t)tid*3 + 1], red);
    if (tid == 0) out[128 + g*3 + 1] = s1 + rl_b2[1];
    float s2 = blk_sum256(t * rl_w2[(size_t)tid*3 + 2], red);
    if (tid == 0) out[128 + g*3 + 2] = s2 + rl_b2[2];
}

// ---------------------------------------------------------------------------
extern "C" void kernel_launch(void* const* d_in, const int* in_sizes, int n_in,
                              void* d_out, int out_size, void* d_ws, size_t ws_size,
                              hipStream_t stream)
{
    const float* x      = (const float*)d_in[0];
    const float* pos    = (const float*)d_in[1];
    const float* W1     = (const float*)d_in[2];
    const float* b1     = (const float*)d_in[3];
    const float* W2     = (const float*)d_in[4];
    const float* b2     = (const float*)d_in[5];
    const float* W3     = (const float*)d_in[6];
    const float* b3     = (const float*)d_in[7];
    const float* g1     = (const float*)d_in[8];
    const float* be1    = (const float*)d_in[9];
    const float* m1     = (const float*)d_in[10];
    const float* v1     = (const float*)d_in[11];
    const float* g2     = (const float*)d_in[12];
    const float* be2    = (const float*)d_in[13];
    const float* m2     = (const float*)d_in[14];
    const float* v2     = (const float*)d_in[15];
    const float* g3     = (const float*)d_in[16];
    const float* be3    = (const float*)d_in[17];
    const float* m3     = (const float*)d_in[18];
    const float* v3     = (const float*)d_in[19];
    const float* gate_w = (const float*)d_in[20];
    const float* gate_b = (const float*)d_in[21];
    const float* aff_w  = (const float*)d_in[22];
    const float* aff_b  = (const float*)d_in[23];
    const float* rl_w1  = (const float*)d_in[24];
    const float* rl_b1  = (const float*)d_in[25];
    const float* rl_w2  = (const float*)d_in[26];
    const float* rl_b2  = (const float*)d_in[27];
    float* out = (float*)d_out;

    // workspace layout (~135.7 MB extent, unchanged)
    char* wsb = (char*)d_ws;
    unsigned short* nbr = (unsigned short*)wsb;               // 786,432 B
    char* Wimg1 = wsb + 786432;                               // 163,840 B
    char* Wimg2 = Wimg1 + (size_t)2*NSTEP1*16384;             // 262,144 B
    char* Wimg3 = Wimg2 + (size_t)2*8*16384;                  // 262,144 B
    float* h_a  = (float*)(Wimg3 + (size_t)2*8*16384);        // 67.1 MB
    char* regB  = (char*)(h_a + (size_t)NB_TOT*HF);           // 67.1 MB
    // gatep (128 KB) aliases Wimg1 (dead after gemm1; layer-3 gcn_fused,
    // its writer, is stream-ordered after gemm1).
    float* gatep = (float*)Wimg1;
    // region B: agg_first's Aimg -> gemm1 reads -> h_b overwrites ->
    // layer3 reads h_b -> gembp overwrites in readout.
    char*  Aimg  = regB;
    float* h_b   = (float*)regB;
    float* gembp = (float*)regB;

    knn_kernel<<<NBG*8, 256, 0, stream>>>(pos, nbr);
    prew_all<<<84, 256, 0, stream>>>(W1, W2, W3, Wimg1, Wimg2, Wimg3);

    agg_first<<<(NB_TOT*20)/256, 256, 0, stream>>>(x, pos, nbr, Aimg);
    gemm_mfma<<<dim3(NB_TOT/128, 2), 256, 0, stream>>>(Aimg, Wimg1, NSTEP1,
        b1, g1, be1, m1, v1, h_a);
    gcn_fused<<<NB_TOT/64, 256, 0, stream>>>(h_a, nbr, Wimg2,
        b2, g2, be2, m2, v2, h_b, gate_w, nullptr);
    gcn_fused<<<NB_TOT/64, 256, 0, stream>>>(h_b, nbr, Wimg3,
        b3, g3, be3, m3, v3, h_a, gate_w, gatep);

    gemb_kernel<<<dim3(NBG, 4), 256, 0, stream>>>(h_a, gatep, gate_b, gembp);
    heads_kernel<<<NBG, 256, 0, stream>>>(gembp, aff_w, aff_b,
                                          rl_w1, rl_b1, rl_w2, rl_b2, out);
}